// Round 6
// baseline (9597.355 us; speedup 1.0000x reference)
//
#include <hip/hip_runtime.h>

// CGIterator: N=50000 nodes, K=128, I=4 chained CG iterations, fp32.
// Round-6 theory: all prior kernels were L2-BW-bound on redundant weight
// streaming (every block reads full W_in/W_out from L2; ~8-11 TB/s observed
// regardless of structure). Fix = amortize: NB=4 nodes/block, 12500 blocks
// -> per-block weight traffic unchanged, total halved vs round 5.
//  - 256 threads, thread owns column p for lin_in (acc[4][9]=36 regs)
//  - 12 FMA per weight load in BOTH linear layers (was 6)
//  - single-buffered 12-reg weight batches (round-5-proven, no spill)
//  - per-node TP to cap live regs (~90); f-skip in registers (2 nodes/thread)
//  - p-split lin_out + 18-float exchange (round-2 scheme, aliased on dead s_h)

#define NNODES 50000
#define KCH 128          // K
#define PCH 256          // 2K
#define NITER 4
#define NB 4             // nodes per block
#define NTHR 256

__global__ __launch_bounds__(NTHR, 2)
void cg_fused(const float* __restrict__ f0,
              const float* __restrict__ f1,
              const float* __restrict__ f2,
              const float* __restrict__ Uin,
              const float* __restrict__ gamma,
              const float* __restrict__ W_in,
              const float* __restrict__ W_out,
              float* __restrict__ out)
{
    // symmetrized U, upper triangle a<=b packed: sUp[ab][c], c padded to 12
    __shared__ float sUp[45][12];                 // 2.1 KB
    __shared__ float s_h[NB][9][KCH];             // 18.4 KB; dead after lin_in,
                                                  // aliased as exchange buffer
    __shared__ float s_tp[NB][9][PCH];            // 36.9 KB, TP output
    // total 57.4 KB -> 2 blocks/CU

    // exchange view: s_red[half][j=node2*9+m][kk], 2*18*128*4B == sizeof(s_h)
    float (*s_red)[18][KCH] = reinterpret_cast<float (*)[18][KCH]>(&s_h[0][0][0]);

    const int tid = threadIdx.x;      // 0..255
    const int kk  = tid & (KCH - 1);  // channel 0..127
    const int nh  = tid >> 7;         // node-pair / p-half: 0 or 1 (wave-uniform)
    const int p   = tid;              // expanded channel column 0..255
    const int node0 = blockIdx.x * NB;

    // ---- build symmetrized padded U in LDS (once per block)
    for (int idx = tid; idx < 45 * 12; idx += NTHR) {
        const int ab = idx / 12;
        const int c  = idx % 12;
        int a = 0, r = ab;
        while (r >= 9 - a) { r -= 9 - a; ++a; }
        const int b = a + r;
        float v = 0.0f;
        if (c < 9) {
            v = Uin[(a * 9 + b) * 9 + c];
            if (a != b) v += Uin[(b * 9 + a) * 9 + c];
        }
        sUp[ab][c] = v;
    }

    // ---- initial feats: thread owns nodes 2*nh+{0,1} at channel kk, all 9 m
    float f[2][9];
    #pragma unroll
    for (int j = 0; j < 2; ++j) {
        const int ng = node0 + 2 * nh + j;
        f[j][0] = f0[ng * KCH + kk];
        #pragma unroll
        for (int m = 0; m < 3; ++m) f[j][1 + m] = f1[(ng * 3 + m) * KCH + kk];
        #pragma unroll
        for (int m = 0; m < 5; ++m) f[j][4 + m] = f2[(ng * 5 + m) * KCH + kk];
    }

    for (int it = 0; it < NITER; ++it) {
        // ---------- step 1: equivariant RMS norm -> s_h ----------
        {
            const float g0 = gamma[(it * 3 + 0) * KCH + kk];
            const float g1 = gamma[(it * 3 + 1) * KCH + kk];
            const float g2 = gamma[(it * 3 + 2) * KCH + kk];
            #pragma unroll
            for (int j = 0; j < 2; ++j) {
                const int nl = 2 * nh + j;
                const float s0 = f[j][0] * f[j][0];
                const float s1 = f[j][1] * f[j][1] + f[j][2] * f[j][2] + f[j][3] * f[j][3];
                const float s2 = f[j][4] * f[j][4] + f[j][5] * f[j][5] + f[j][6] * f[j][6]
                               + f[j][7] * f[j][7] + f[j][8] * f[j][8];
                const float r0 = rsqrtf(s0 + 1e-6f) * g0;
                const float r1 = rsqrtf(s1 * (1.0f / 3.0f) + 1e-6f) * g1;
                const float r2 = rsqrtf(s2 * (1.0f / 5.0f) + 1e-6f) * g2;
                s_h[nl][0][kk] = f[j][0] * r0;
                s_h[nl][1][kk] = f[j][1] * r1;
                s_h[nl][2][kk] = f[j][2] * r1;
                s_h[nl][3][kk] = f[j][3] * r1;
                s_h[nl][4][kk] = f[j][4] * r2;
                s_h[nl][5][kk] = f[j][5] * r2;
                s_h[nl][6][kk] = f[j][6] * r2;
                s_h[nl][7][kk] = f[j][7] * r2;
                s_h[nl][8][kk] = f[j][8] * r2;
            }
        }
        __syncthreads();   // s_h visible (also orders sUp build on it==0)

        // ---------- step 2: linear_in, l-fused, K-step 4, 4-node amortization
        float hc[NB][9];   // this thread's hc column p — stays in registers for TP
        {
            const float* W0 = W_in + (size_t)(it * 3 + 0) * KCH * PCH + p;
            const float* W1 = W_in + (size_t)(it * 3 + 1) * KCH * PCH + p;
            const float* W2 = W_in + (size_t)(it * 3 + 2) * KCH * PCH + p;
            #pragma unroll
            for (int n = 0; n < NB; ++n)
                #pragma unroll
                for (int m = 0; m < 9; ++m) hc[n][m] = 0.0f;

            #pragma unroll 1
            for (int kb = 0; kb < KCH; kb += 4) {
                float wv[3][4];
                #pragma unroll
                for (int r = 0; r < 4; ++r) {
                    wv[0][r] = W0[(kb + r) * PCH];
                    wv[1][r] = W1[(kb + r) * PCH];
                    wv[2][r] = W2[(kb + r) * PCH];
                }
                #pragma unroll
                for (int n = 0; n < NB; ++n) {
                    #pragma unroll
                    for (int m = 0; m < 9; ++m) {
                        const int lm = (m == 0) ? 0 : ((m < 4) ? 1 : 2);
                        const float4 h4 = *(const float4*)&s_h[n][m][kb];
                        float a = hc[n][m];
                        a = fmaf(h4.x, wv[lm][0], a);
                        a = fmaf(h4.y, wv[lm][1], a);
                        a = fmaf(h4.z, wv[lm][2], a);
                        a = fmaf(h4.w, wv[lm][3], a);
                        hc[n][m] = a;
                    }
                }
            }
        }

        // ---------- step 3: CG tensor product, per node (caps live registers)
        {
            #pragma unroll
            for (int n = 0; n < NB; ++n) {
                float tp9[9];
                #pragma unroll
                for (int c = 0; c < 9; ++c) tp9[c] = 0.0f;
                int ab = 0;
                #pragma unroll
                for (int a = 0; a < 9; ++a) {
                    #pragma unroll
                    for (int b = a; b < 9; ++b) {
                        const float q = hc[n][a] * hc[n][b];
                        const float4 u0 = *(const float4*)&sUp[ab][0];
                        const float4 u1 = *(const float4*)&sUp[ab][4];
                        const float  u8 = sUp[ab][8];
                        tp9[0] = fmaf(u0.x, q, tp9[0]);
                        tp9[1] = fmaf(u0.y, q, tp9[1]);
                        tp9[2] = fmaf(u0.z, q, tp9[2]);
                        tp9[3] = fmaf(u0.w, q, tp9[3]);
                        tp9[4] = fmaf(u1.x, q, tp9[4]);
                        tp9[5] = fmaf(u1.y, q, tp9[5]);
                        tp9[6] = fmaf(u1.z, q, tp9[6]);
                        tp9[7] = fmaf(u1.w, q, tp9[7]);
                        tp9[8] = fmaf(u8,  q, tp9[8]);
                        ++ab;
                    }
                }
                #pragma unroll
                for (int c = 0; c < 9; ++c) s_tp[n][c][p] = tp9[c];
            }
        }
        __syncthreads();   // tp visible to all columns; also: all lin_in s_h
                           // reads complete -> s_red may overwrite s_h below

        // ---------- step 4: linear_out, p-split + l-fused, 4-node amortization
        {
            const float* V0 = W_out + (size_t)(it * 3 + 0) * PCH * KCH + kk;
            const float* V1 = W_out + (size_t)(it * 3 + 1) * PCH * KCH + kk;
            const float* V2 = W_out + (size_t)(it * 3 + 2) * PCH * KCH + kk;
            const int pb0 = nh * 128;   // this half's p-range (wave-uniform)

            float oacc[NB][9];
            #pragma unroll
            for (int n = 0; n < NB; ++n)
                #pragma unroll
                for (int m = 0; m < 9; ++m) oacc[n][m] = 0.0f;

            #pragma unroll 1
            for (int pb = 0; pb < 128; pb += 4) {
                float vv[3][4];
                #pragma unroll
                for (int r = 0; r < 4; ++r) {
                    const size_t row = (size_t)(pb0 + pb + r) * KCH;
                    vv[0][r] = V0[row];
                    vv[1][r] = V1[row];
                    vv[2][r] = V2[row];
                }
                #pragma unroll
                for (int n = 0; n < NB; ++n) {
                    #pragma unroll
                    for (int m = 0; m < 9; ++m) {
                        const int lm = (m == 0) ? 0 : ((m < 4) ? 1 : 2);
                        const float4 t4 = *(const float4*)&s_tp[n][m][pb0 + pb];
                        float a = oacc[n][m];
                        a = fmaf(t4.x, vv[lm][0], a);
                        a = fmaf(t4.y, vv[lm][1], a);
                        a = fmaf(t4.z, vv[lm][2], a);
                        a = fmaf(t4.w, vv[lm][3], a);
                        oacc[n][m] = a;
                    }
                }
            }

            // exchange: hand the other half the partials for ITS 2 nodes.
            // s_red aliases dead s_h; lane-consecutive addresses, no conflicts.
            if (nh == 0) {
                #pragma unroll
                for (int j = 0; j < 18; ++j)
                    s_red[0][j][kk] = oacc[2 + j / 9][j % 9];   // nodes 2,3
            } else {
                #pragma unroll
                for (int j = 0; j < 18; ++j)
                    s_red[1][j][kk] = oacc[j / 9][j % 9];       // nodes 0,1
            }
            __syncthreads();

            const int ob = 1 - nh;   // buffer written by the other half
            #pragma unroll
            for (int j = 0; j < 2; ++j) {
                const int nl = 2 * nh + j;
                #pragma unroll
                for (int m = 0; m < 9; ++m)
                    f[j][m] += oacc[nl][m] + s_red[ob][j * 9 + m][kk];
            }
        }
        __syncthreads();   // s_red reads done before next iter's RMS rewrites s_h
    }

    // ---------- store packed output (N, 9, K)
    #pragma unroll
    for (int j = 0; j < 2; ++j) {
        const int ng = node0 + 2 * nh + j;
        #pragma unroll
        for (int m = 0; m < 9; ++m)
            out[(size_t)(ng * 9 + m) * KCH + kk] = f[j][m];
    }
}

extern "C" void kernel_launch(void* const* d_in, const int* in_sizes, int n_in,
                              void* d_out, int out_size, void* d_ws, size_t ws_size,
                              hipStream_t stream) {
    const float* f0    = (const float*)d_in[0];
    const float* f1    = (const float*)d_in[1];
    const float* f2    = (const float*)d_in[2];
    const float* U     = (const float*)d_in[3];
    const float* gamma = (const float*)d_in[4];
    const float* W_in  = (const float*)d_in[5];
    const float* W_out = (const float*)d_in[6];
    float* out = (float*)d_out;

    dim3 grid(NNODES / NB);   // 50000 / 4 = 12500, exact
    dim3 block(NTHR);
    hipLaunchKernelGGL(cg_fused, grid, block, 0, stream,
                       f0, f1, f2, U, gamma, W_in, W_out, out);
}

// Round 7
// 4997.904 us; speedup vs baseline: 1.9203x; 1.9203x over previous
//
#include <hip/hip_runtime.h>

// CGIterator: N=50000 nodes, K=128, I=4 chained CG iterations, fp32.
// Round-7 probe: per-CU VMEM-*instruction* throughput theory.
// Round-5 skeleton (128 thr, NB=2, TN=2, 72 VGPR, no spill) with weight
// loads widened to float2 (thread owns consecutive columns 2t,2t+1):
// halves VMEM instructions at identical bytes. If instr-rate-bound -> ~1.5x;
// if byte-bound -> flat, and round 8 attacks bytes instead.

#define NNODES 50000
#define KCH 128          // K
#define PCH 256          // 2K
#define NITER 4
#define NB 2             // nodes per block
#define NTHR 128

__global__ __launch_bounds__(NTHR, 4)
void cg_fused(const float* __restrict__ f0,
              const float* __restrict__ f1,
              const float* __restrict__ f2,
              const float* __restrict__ Uin,
              const float* __restrict__ gamma,
              const float* __restrict__ W_in,
              const float* __restrict__ W_out,
              float* __restrict__ out)
{
    // symmetrized U, upper triangle a<=b packed: sUp[ab][c], c padded to 12
    __shared__ float sUp[45][12];                 // 2.1 KB
    __shared__ float s_h[NB][9][KCH];             // 9.2 KB
    __shared__ float s_tp[NB][9][PCH];            // 18.4 KB; dead after lin_out
                                                  // reads -> reused for exchange
    // exchange view over s_tp: s_part[wave][j=n*9+m][kk], 2*18*128*4B = 18.4KB
    float (*s_part)[18][KCH] = reinterpret_cast<float (*)[18][KCH]>(&s_tp[0][0][0]);

    const int tid = threadIdx.x;      // 0..127
    const int w   = tid >> 6;         // wave: 0 or 1 (uniform per wave)
    const int ln  = tid & 63;
    const int kk  = tid;              // owned channel for RMS/skip/output
    const int node0 = blockIdx.x * NB;

    // ---- build symmetrized padded U in LDS (once per block)
    for (int idx = tid; idx < 45 * 12; idx += NTHR) {
        const int ab = idx / 12;
        const int c  = idx % 12;
        int a = 0, r = ab;
        while (r >= 9 - a) { r -= 9 - a; ++a; }
        const int b = a + r;
        float v = 0.0f;
        if (c < 9) {
            v = Uin[(a * 9 + b) * 9 + c];
            if (a != b) v += Uin[(b * 9 + a) * 9 + c];
        }
        sUp[ab][c] = v;
    }

    // ---- initial feats: thread owns channel kk for BOTH nodes, all 9 m
    float f[NB][9];
    #pragma unroll
    for (int n = 0; n < NB; ++n) {
        const int ng = node0 + n;
        f[n][0] = f0[ng * KCH + kk];
        #pragma unroll
        for (int m = 0; m < 3; ++m) f[n][1 + m] = f1[(ng * 3 + m) * KCH + kk];
        #pragma unroll
        for (int m = 0; m < 5; ++m) f[n][4 + m] = f2[(ng * 5 + m) * KCH + kk];
    }

    for (int it = 0; it < NITER; ++it) {
        // ---------- step 1: equivariant RMS norm -> s_h ----------
        {
            const float g0 = gamma[(it * 3 + 0) * KCH + kk];
            const float g1 = gamma[(it * 3 + 1) * KCH + kk];
            const float g2 = gamma[(it * 3 + 2) * KCH + kk];
            #pragma unroll
            for (int n = 0; n < NB; ++n) {
                const float s0 = f[n][0] * f[n][0];
                const float s1 = f[n][1] * f[n][1] + f[n][2] * f[n][2] + f[n][3] * f[n][3];
                const float s2 = f[n][4] * f[n][4] + f[n][5] * f[n][5] + f[n][6] * f[n][6]
                               + f[n][7] * f[n][7] + f[n][8] * f[n][8];
                const float r0 = rsqrtf(s0 + 1e-6f) * g0;
                const float r1 = rsqrtf(s1 * (1.0f / 3.0f) + 1e-6f) * g1;
                const float r2 = rsqrtf(s2 * (1.0f / 5.0f) + 1e-6f) * g2;
                s_h[n][0][kk] = f[n][0] * r0;
                s_h[n][1][kk] = f[n][1] * r1;
                s_h[n][2][kk] = f[n][2] * r1;
                s_h[n][3][kk] = f[n][3] * r1;
                s_h[n][4][kk] = f[n][4] * r2;
                s_h[n][5][kk] = f[n][5] * r2;
                s_h[n][6][kk] = f[n][6] * r2;
                s_h[n][7][kk] = f[n][7] * r2;
                s_h[n][8][kk] = f[n][8] * r2;
            }
        }
        __syncthreads();   // s_h visible (also orders sUp build on it==0)

        // ---------- step 2: linear_in, 2 CONSECUTIVE columns/thread (2t, 2t+1)
        //            weight loads are float2 (dwordx2): half the VMEM instrs
        float hcA[NB][9], hcB[NB][9];   // A = col 2t, B = col 2t+1
        {
            const float* W0 = W_in + (size_t)(it * 3 + 0) * KCH * PCH + 2 * tid;
            const float* W1 = W_in + (size_t)(it * 3 + 1) * KCH * PCH + 2 * tid;
            const float* W2 = W_in + (size_t)(it * 3 + 2) * KCH * PCH + 2 * tid;
            #pragma unroll
            for (int n = 0; n < NB; ++n)
                #pragma unroll
                for (int m = 0; m < 9; ++m) { hcA[n][m] = 0.0f; hcB[n][m] = 0.0f; }

            #pragma unroll 1
            for (int kb = 0; kb < KCH; kb += 4) {
                float2 wv[3][4];
                #pragma unroll
                for (int r = 0; r < 4; ++r) {
                    wv[0][r] = *(const float2*)&W0[(kb + r) * PCH];
                    wv[1][r] = *(const float2*)&W1[(kb + r) * PCH];
                    wv[2][r] = *(const float2*)&W2[(kb + r) * PCH];
                }
                #pragma unroll
                for (int n = 0; n < NB; ++n) {
                    #pragma unroll
                    for (int m = 0; m < 9; ++m) {
                        const int lm = (m == 0) ? 0 : ((m < 4) ? 1 : 2);
                        const float4 h4 = *(const float4*)&s_h[n][m][kb];
                        float a = hcA[n][m], b = hcB[n][m];
                        a = fmaf(h4.x, wv[lm][0].x, a);
                        a = fmaf(h4.y, wv[lm][1].x, a);
                        a = fmaf(h4.z, wv[lm][2].x, a);
                        a = fmaf(h4.w, wv[lm][3].x, a);
                        b = fmaf(h4.x, wv[lm][0].y, b);
                        b = fmaf(h4.y, wv[lm][1].y, b);
                        b = fmaf(h4.z, wv[lm][2].y, b);
                        b = fmaf(h4.w, wv[lm][3].y, b);
                        hcA[n][m] = a; hcB[n][m] = b;
                    }
                }
            }
        }

        // ---------- step 3: CG tensor product, both columns in registers ----------
        {
            float tpA[NB][9], tpB[NB][9];
            #pragma unroll
            for (int n = 0; n < NB; ++n)
                #pragma unroll
                for (int c = 0; c < 9; ++c) { tpA[n][c] = 0.0f; tpB[n][c] = 0.0f; }

            int ab = 0;
            #pragma unroll
            for (int a = 0; a < 9; ++a) {
                #pragma unroll
                for (int b = a; b < 9; ++b) {
                    const float qA0 = hcA[0][a] * hcA[0][b];
                    const float qA1 = hcA[1][a] * hcA[1][b];
                    const float qB0 = hcB[0][a] * hcB[0][b];
                    const float qB1 = hcB[1][a] * hcB[1][b];
                    const float4 u0 = *(const float4*)&sUp[ab][0];
                    const float4 u1 = *(const float4*)&sUp[ab][4];
                    const float  u8 = sUp[ab][8];
                    const float uu[9] = {u0.x, u0.y, u0.z, u0.w, u1.x, u1.y, u1.z, u1.w, u8};
                    #pragma unroll
                    for (int c = 0; c < 9; ++c) {
                        tpA[0][c] = fmaf(uu[c], qA0, tpA[0][c]);
                        tpA[1][c] = fmaf(uu[c], qA1, tpA[1][c]);
                        tpB[0][c] = fmaf(uu[c], qB0, tpB[0][c]);
                        tpB[1][c] = fmaf(uu[c], qB1, tpB[1][c]);
                    }
                    ++ab;
                }
            }
            // paired columns -> single ds_write_b64 each (2-way bank alias: free)
            #pragma unroll
            for (int n = 0; n < NB; ++n) {
                #pragma unroll
                for (int c = 0; c < 9; ++c) {
                    float2 t2; t2.x = tpA[n][c]; t2.y = tpB[n][c];
                    *(float2*)&s_tp[n][c][2 * tid] = t2;
                }
            }
        }
        __syncthreads();   // s_tp visible to all columns

        // ---------- step 4: linear_out, p-half per wave, 2 consecutive kk/thread
        float oaA[NB][9], oaB[NB][9];   // kkA = 2*ln, kkB = 2*ln+1
        {
            const float* V0 = W_out + (size_t)(it * 3 + 0) * PCH * KCH + 2 * ln;
            const float* V1 = W_out + (size_t)(it * 3 + 1) * PCH * KCH + 2 * ln;
            const float* V2 = W_out + (size_t)(it * 3 + 2) * PCH * KCH + 2 * ln;
            const int pb0 = w * 128;   // this wave's p-half (uniform)

            #pragma unroll
            for (int n = 0; n < NB; ++n)
                #pragma unroll
                for (int m = 0; m < 9; ++m) { oaA[n][m] = 0.0f; oaB[n][m] = 0.0f; }

            #pragma unroll 1
            for (int pb = 0; pb < 128; pb += 4) {
                float2 vv[3][4];
                #pragma unroll
                for (int r = 0; r < 4; ++r) {
                    const size_t row = (size_t)(pb0 + pb + r) * KCH;
                    vv[0][r] = *(const float2*)&V0[row];
                    vv[1][r] = *(const float2*)&V1[row];
                    vv[2][r] = *(const float2*)&V2[row];
                }
                #pragma unroll
                for (int n = 0; n < NB; ++n) {
                    #pragma unroll
                    for (int m = 0; m < 9; ++m) {
                        const int lm = (m == 0) ? 0 : ((m < 4) ? 1 : 2);
                        const float4 t4 = *(const float4*)&s_tp[n][m][pb0 + pb];
                        float a = oaA[n][m], b = oaB[n][m];
                        a = fmaf(t4.x, vv[lm][0].x, a);
                        a = fmaf(t4.y, vv[lm][1].x, a);
                        a = fmaf(t4.z, vv[lm][2].x, a);
                        a = fmaf(t4.w, vv[lm][3].x, a);
                        b = fmaf(t4.x, vv[lm][0].y, b);
                        b = fmaf(t4.y, vv[lm][1].y, b);
                        b = fmaf(t4.z, vv[lm][2].y, b);
                        b = fmaf(t4.w, vv[lm][3].y, b);
                        oaA[n][m] = a; oaB[n][m] = b;
                    }
                }
            }
        }
        __syncthreads();   // ALL s_tp reads done -> safe to overwrite as s_part

        // exchange: both waves write their partials for their kk-pair; each
        // thread then sums the two wave-partials at its own kk column.
        #pragma unroll
        for (int n = 0; n < NB; ++n) {
            #pragma unroll
            for (int m = 0; m < 9; ++m) {
                float2 t2; t2.x = oaA[n][m]; t2.y = oaB[n][m];
                *(float2*)&s_part[w][n * 9 + m][2 * ln] = t2;
            }
        }
        __syncthreads();

        #pragma unroll
        for (int n = 0; n < NB; ++n)
            #pragma unroll
            for (int m = 0; m < 9; ++m)
                f[n][m] += s_part[0][n * 9 + m][kk] + s_part[1][n * 9 + m][kk];
        __syncthreads();   // s_part reads done before next iter's TP rewrites s_tp
    }

    // ---------- store packed output (N, 9, K)
    #pragma unroll
    for (int n = 0; n < NB; ++n) {
        const int ng = node0 + n;
        #pragma unroll
        for (int m = 0; m < 9; ++m)
            out[(size_t)(ng * 9 + m) * KCH + kk] = f[n][m];
    }
}

extern "C" void kernel_launch(void* const* d_in, const int* in_sizes, int n_in,
                              void* d_out, int out_size, void* d_ws, size_t ws_size,
                              hipStream_t stream) {
    const float* f0    = (const float*)d_in[0];
    const float* f1    = (const float*)d_in[1];
    const float* f2    = (const float*)d_in[2];
    const float* U     = (const float*)d_in[3];
    const float* gamma = (const float*)d_in[4];
    const float* W_in  = (const float*)d_in[5];
    const float* W_out = (const float*)d_in[6];
    float* out = (float*)d_out;

    dim3 grid(NNODES / NB);   // 50000 / 2 = 25000, exact
    dim3 block(NTHR);
    hipLaunchKernelGGL(cg_fused, grid, block, 0, stream,
                       f0, f1, f2, U, gamma, W_in, W_out, out);
}